// Round 1
// baseline (259.406 us; speedup 1.0000x reference)
//
#include <hip/hip_runtime.h>
#include <cstdint>
#include <cstddef>

// ---------------- problem constants (fixed by setup_inputs) ----------------
#define B_  4
#define T_  2048
#define D_  512
#define NH_ 8
#define HD_ 64
#define FF_ 2048
#define M_  (B_*T_)   // 8192 token rows

typedef unsigned short u16;
typedef __attribute__((ext_vector_type(8))) unsigned short u16x8;
typedef __attribute__((ext_vector_type(8))) __bf16         bf16x8;
typedef __attribute__((ext_vector_type(4))) float          f32x4;

__device__ __forceinline__ u16 f2bf(float f) {            // RNE f32 -> bf16
  unsigned u = __float_as_uint(f);
  u += 0x7FFF + ((u >> 16) & 1);
  return (u16)(u >> 16);
}

__device__ __forceinline__ f32x4 mfma_bf16(u16x8 a, u16x8 b, f32x4 c) {
  return __builtin_amdgcn_mfma_f32_16x16x32_bf16(
      __builtin_bit_cast(bf16x8, a), __builtin_bit_cast(bf16x8, b), c, 0, 0, 0);
}

// async global->LDS, 16B per lane; LDS dest = wave-uniform base + lane*16
__device__ __forceinline__ void async16(const void* g, void* l) {
  __builtin_amdgcn_global_load_lds(
      (const __attribute__((address_space(1))) unsigned int*)g,
      (__attribute__((address_space(3))) unsigned int*)l, 16, 0, 0);
}

// ---- transpose + cast: in [R][C] f32 -> out [C][R] bf16 (weights are [K][N])
__global__ __launch_bounds__(256) void trans_kernel(const float* __restrict__ in,
                                                    u16* __restrict__ out,
                                                    int R, int C) {
  __shared__ float tile[32][33];
  int c0 = blockIdx.x * 32, r0 = blockIdx.y * 32;
  int tx = threadIdx.x, ty = threadIdx.y;  // block (32,8)
#pragma unroll
  for (int i = 0; i < 4; i++)
    tile[ty + i * 8][tx] = in[(size_t)(r0 + ty + i * 8) * C + c0 + tx];
  __syncthreads();
#pragma unroll
  for (int i = 0; i < 4; i++)
    out[(size_t)(c0 + ty + i * 8) * R + r0 + tx] = f2bf(tile[tx][ty + i * 8]);
}

// ---- rmsnorm over rows of 512, fp32 in -> bf16 out. 1 wave per row.
__global__ __launch_bounds__(256) void rmsnorm_kernel(const float* __restrict__ x,
                                                      const float* __restrict__ w,
                                                      u16* __restrict__ out) {
  int row  = blockIdx.x * 4 + (threadIdx.x >> 6);
  int lane = threadIdx.x & 63;
  const float* xr = x + (size_t)row * D_ + lane * 8;
  float4 v0 = *(const float4*)xr;
  float4 v1 = *(const float4*)(xr + 4);
  float ss = v0.x*v0.x + v0.y*v0.y + v0.z*v0.z + v0.w*v0.w
           + v1.x*v1.x + v1.y*v1.y + v1.z*v1.z + v1.w*v1.w;
#pragma unroll
  for (int m = 1; m < 64; m <<= 1) ss += __shfl_xor(ss, m, 64);
  float inv = rsqrtf(ss * (1.0f / D_) + 1e-6f);
  const float* wr = w + lane * 8;
  float4 w0 = *(const float4*)wr;
  float4 w1v = *(const float4*)(wr + 4);
  u16 o[8];
  o[0] = f2bf(v0.x * inv * w0.x);  o[1] = f2bf(v0.y * inv * w0.y);
  o[2] = f2bf(v0.z * inv * w0.z);  o[3] = f2bf(v0.w * inv * w0.w);
  o[4] = f2bf(v1.x * inv * w1v.x); o[5] = f2bf(v1.y * inv * w1v.y);
  o[6] = f2bf(v1.z * inv * w1v.z); o[7] = f2bf(v1.w * inv * w1v.w);
  *(uint4*)(out + (size_t)row * D_ + lane * 8) = *(uint4*)o;
}

// ---- m97-style bf16 MFMA GEMM: C[M,N] = A[M,K] * Bt[N,K]^T (+bias)(gelu)(+res)
// 128x128 tile, BK=32, 256 threads = 4 waves (2x2), 64x64 per wave.
template <bool HAS_BIAS, bool HAS_RES, bool DO_GELU, bool STORE_BF16>
__global__ __launch_bounds__(256) void gemm_kernel(
    const u16* __restrict__ A, const u16* __restrict__ Bt, void* __restrict__ Cv,
    const float* __restrict__ bias, const float* __restrict__ res,
    int M, int N, int K) {
  __shared__ __align__(16) char smem[16384];
  u16* ldsA = (u16*)smem;            // [128][32]
  u16* ldsB = (u16*)(smem + 8192);   // [128][32]
  const int tid = threadIdx.x;
  const int lane = tid & 63, w = tid >> 6;
  const int quad = lane >> 4, m16 = lane & 15;
  const int wm = w & 1, wn = w >> 1;
  const int m0 = blockIdx.y * 128, n0 = blockIdx.x * 128;

  f32x4 acc[4][4];
#pragma unroll
  for (int i = 0; i < 4; i++)
#pragma unroll
    for (int j = 0; j < 4; j++) acc[i][j] = (f32x4){0.f, 0.f, 0.f, 0.f};

  const int arow = tid >> 2;          // 0..63
  const int ac   = (tid & 3) * 8;     // k-chunk within BK
  const u16* Ag0 = A  + (size_t)(m0 + arow) * K + ac;
  const u16* Ag1 = Ag0 + (size_t)64 * K;
  const u16* Bg0 = Bt + (size_t)(n0 + arow) * K + ac;
  const u16* Bg1 = Bg0 + (size_t)64 * K;
  char* la0 = smem + tid * 16;
  char* la1 = smem + 4096 + tid * 16;
  char* lb0 = smem + 8192 + tid * 16;
  char* lb1 = smem + 12288 + tid * 16;

  for (int kt = 0; kt < K; kt += 32) {
    async16(Ag0 + kt, la0);
    async16(Ag1 + kt, la1);
    async16(Bg0 + kt, lb0);
    async16(Bg1 + kt, lb1);
    __syncthreads();   // vmcnt(0) drain before reads
    const u16* pa = ldsA + (wm * 64 + m16) * 32 + quad * 8;
    const u16* pb = ldsB + (wn * 64 + m16) * 32 + quad * 8;
    u16x8 af[4], bfr[4];
#pragma unroll
    for (int i = 0; i < 4; i++) af[i] = *(const u16x8*)(pa + i * 512);
#pragma unroll
    for (int j = 0; j < 4; j++) bfr[j] = *(const u16x8*)(pb + j * 512);
#pragma unroll
    for (int i = 0; i < 4; i++)
#pragma unroll
      for (int j = 0; j < 4; j++)
        acc[i][j] = mfma_bf16(af[i], bfr[j], acc[i][j]);
    __syncthreads();   // LDS reads done before next stage overwrites
  }

  // epilogue: D[row=quad*4+r][col=m16] per 16x16 subtile
#pragma unroll
  for (int j = 0; j < 4; j++) {
    int nn = n0 + wn * 64 + j * 16 + m16;
    float bv = HAS_BIAS ? bias[nn] : 0.0f;
#pragma unroll
    for (int i = 0; i < 4; i++) {
      int mmb = m0 + wm * 64 + i * 16 + quad * 4;
#pragma unroll
      for (int r = 0; r < 4; r++) {
        float v = acc[i][j][r] + bv;
        if (DO_GELU) v = 0.5f * v * (1.0f + erff(v * 0.70710678118f));
        size_t idx = (size_t)(mmb + r) * N + nn;
        if (HAS_RES) v += res[idx];
        if (STORE_BF16) ((u16*)Cv)[idx] = f2bf(v);
        else            ((float*)Cv)[idx] = v;
      }
    }
  }
}

// ---- banded attention, MFMA flash-style, full-window softmax in registers.
// grid (T/64, NH, B), 256 threads = 4 waves, each wave owns 16 queries.
// qkv bf16 [B*T][1536]: q at col 0, k at 512, v at 1024 (+h*64).
__global__ __launch_bounds__(256) void attn_kernel(const u16* __restrict__ qkv,
                                                   u16* __restrict__ out) {
  __shared__ __align__(16) char smem[54272];
  u16* Ks = (u16*)smem;               // [208][64] keys (26624 B)
  u16* Vt = (u16*)(smem + 26624);     // [64][216] V transposed (27648 B)
  const int tid = threadIdx.x, lane = tid & 63, w = tid >> 6;
  const int quad = lane >> 4, m16 = lane & 15;
  const int q0 = blockIdx.x * 64, h = blockIdx.y, b = blockIdx.z;
  const int kstart = q0 - 64;         // 208-key staging window
  const u16* base = qkv + (size_t)b * T_ * 1536;

  // stage K [208][64]
  for (int c = tid; c < 1664; c += 256) {
    int row = c >> 3, cc = (c & 7) * 8;
    int j = kstart + row;
    j = j < 0 ? 0 : (j > T_ - 1 ? T_ - 1 : j);   // clamp; masked later
    *(uint4*)(Ks + row * 64 + cc) =
        *(const uint4*)(base + (size_t)j * 1536 + 512 + h * 64 + cc);
  }
  // stage V transposed -> Vt[d][key]
  for (int c = tid; c < 1664; c += 256) {
    int row = c >> 3, cc = (c & 7) * 8;
    int j = kstart + row;
    j = j < 0 ? 0 : (j > T_ - 1 ? T_ - 1 : j);
    uint4 u = *(const uint4*)(base + (size_t)j * 1536 + 1024 + h * 64 + cc);
    u16 tmp[8];
    *(uint4*)tmp = u;
#pragma unroll
    for (int i = 0; i < 8; i++) Vt[(cc + i) * 216 + row] = tmp[i];
  }
  // Q fragments straight from global (A-operand layout)
  const int qw = q0 + w * 16;
  const u16* qb = base + (size_t)(qw + m16) * 1536 + h * 64 + quad * 8;
  u16x8 a0 = *(const u16x8*)qb;
  u16x8 a1 = *(const u16x8*)(qb + 32);
  __syncthreads();

  // S = Q K^T over this wave's 160-key window (10 tiles of 16)
  float s[10][4];
#pragma unroll
  for (int t = 0; t < 10; t++) {
    int kt = (w + t) * 16;   // key index in Ks
    u16x8 kb0 = *(const u16x8*)(Ks + (kt + m16) * 64 + quad * 8);
    u16x8 kb1 = *(const u16x8*)(Ks + (kt + m16) * 64 + 32 + quad * 8);
    f32x4 acc = {0.f, 0.f, 0.f, 0.f};
    acc = mfma_bf16(a0, kb0, acc);
    acc = mfma_bf16(a1, kb1, acc);
    int jab = kstart + kt + m16;   // absolute key (col = lane&15)
#pragma unroll
    for (int r = 0; r < 4; r++) {
      int q = qw + quad * 4 + r;
      int d = q - jab;
      bool valid = (jab >= 0) && (jab < T_) && (d <= 64) && (d >= -64);
      s[t][r] = valid ? acc[r] * 0.125f : -1e30f;
    }
  }
  // softmax across 160 keys: per-lane then across the 16 lanes of each quad
  float mx[4], sm[4];
#pragma unroll
  for (int r = 0; r < 4; r++) mx[r] = -1e30f;
#pragma unroll
  for (int t = 0; t < 10; t++)
#pragma unroll
    for (int r = 0; r < 4; r++) mx[r] = fmaxf(mx[r], s[t][r]);
#pragma unroll
  for (int r = 0; r < 4; r++) {
#pragma unroll
    for (int msk = 1; msk < 16; msk <<= 1)
      mx[r] = fmaxf(mx[r], __shfl_xor(mx[r], msk, 64));
    sm[r] = 0.f;
  }
#pragma unroll
  for (int t = 0; t < 10; t++)
#pragma unroll
    for (int r = 0; r < 4; r++) {
      float e = __expf(s[t][r] - mx[r]);
      s[t][r] = e; sm[r] += e;
    }
#pragma unroll
  for (int r = 0; r < 4; r++) {
#pragma unroll
    for (int msk = 1; msk < 16; msk <<= 1) sm[r] += __shfl_xor(sm[r], msk, 64);
    sm[r] = 1.0f / sm[r];
  }
  __syncthreads();                       // all waves done reading Ks
  u16* Ps = (u16*)smem + w * 2688;       // alias Ks region: per-wave [16][168]
#pragma unroll
  for (int t = 0; t < 10; t++)
#pragma unroll
    for (int r = 0; r < 4; r++)
      Ps[(quad * 4 + r) * 168 + t * 16 + m16] = f2bf(s[t][r] * sm[r]);
  __syncthreads();

  // O = P V : A = P[16][32-chunk] (A-layout), B = Vt
  f32x4 o[4];
#pragma unroll
  for (int dt = 0; dt < 4; dt++) o[dt] = (f32x4){0.f, 0.f, 0.f, 0.f};
#pragma unroll
  for (int c5 = 0; c5 < 5; c5++) {
    u16x8 pa = *(const u16x8*)(Ps + m16 * 168 + c5 * 32 + quad * 8);
#pragma unroll
    for (int dt = 0; dt < 4; dt++) {
      u16x8 vb = *(const u16x8*)(Vt + (dt * 16 + m16) * 216 + w * 16 + c5 * 32 + quad * 8);
      o[dt] = mfma_bf16(pa, vb, o[dt]);
    }
  }
#pragma unroll
  for (int dt = 0; dt < 4; dt++)
#pragma unroll
    for (int r = 0; r < 4; r++)
      out[(size_t)(b * T_ + qw + quad * 4 + r) * D_ + h * HD_ + dt * 16 + m16] =
          f2bf(o[dt][r]);
}

// ---------------------------------------------------------------------------
extern "C" void kernel_launch(void* const* d_in, const int* in_sizes, int n_in,
                              void* d_out, int out_size, void* d_ws, size_t ws_size,
                              hipStream_t stream) {
  (void)in_sizes; (void)n_in; (void)out_size; (void)ws_size;
  const float* x     = (const float*)d_in[0];
  const float* n1w   = (const float*)d_in[1];
  const float* n2w   = (const float*)d_in[2];
  const float* w_qkv = (const float*)d_in[3];
  const float* w_out = (const float*)d_in[4];
  const float* b_out = (const float*)d_in[5];
  const float* w1    = (const float*)d_in[6];
  const float* b1    = (const float*)d_in[7];
  const float* w2    = (const float*)d_in[8];
  const float* b2    = (const float*)d_in[9];
  float* out = (float*)d_out;
  char* ws = (char*)d_ws;

  // workspace layout (62 MB; h aliases dead qkv+attnout, hn aliases xn)
  u16* wqkvT  = (u16*)(ws + 0);          // [1536][512]  1.5 MB
  u16* woutT  = (u16*)(ws + 1572864);    // [512][512]   0.5 MB
  u16* w1T    = (u16*)(ws + 2097152);    // [2048][512]  2 MB
  u16* w2T    = (u16*)(ws + 4194304);    // [512][2048]  2 MB
  u16* xn     = (u16*)(ws + 6291456);    // [8192][512]  8 MB (also hn)
  u16* qkv    = (u16*)(ws + 14680064);   // [8192][1536] 24 MB
  u16* attno  = (u16*)(ws + 39845888);   // [8192][512]  8 MB
  float* x1   = (float*)(ws + 48234496); // [8192][512]  16 MB
  u16* hn     = xn;
  u16* hbuf   = qkv;                     // [8192][2048] 32 MB (over qkv+attno)

  dim3 tb(32, 8);
  trans_kernel<<<dim3(48, 16), tb, 0, stream>>>(w_qkv, wqkvT, 512, 1536);
  trans_kernel<<<dim3(16, 16), tb, 0, stream>>>(w_out, woutT, 512, 512);
  trans_kernel<<<dim3(64, 16), tb, 0, stream>>>(w1,   w1T,   512, 2048);
  trans_kernel<<<dim3(16, 64), tb, 0, stream>>>(w2,   w2T,   2048, 512);

  rmsnorm_kernel<<<2048, 256, 0, stream>>>(x, n1w, xn);
  gemm_kernel<false, false, false, true><<<dim3(12, 64), 256, 0, stream>>>(
      xn, wqkvT, (void*)qkv, nullptr, nullptr, M_, 3 * D_, D_);
  attn_kernel<<<dim3(32, 8, 4), 256, 0, stream>>>(qkv, attno);
  gemm_kernel<true, true, false, false><<<dim3(4, 64), 256, 0, stream>>>(
      attno, woutT, (void*)x1, b_out, x, M_, D_, D_);
  rmsnorm_kernel<<<2048, 256, 0, stream>>>(x1, n2w, hn);
  gemm_kernel<true, false, true, true><<<dim3(16, 64), 256, 0, stream>>>(
      hn, w1T, (void*)hbuf, b1, nullptr, M_, FF_, D_);
  gemm_kernel<true, true, false, false><<<dim3(4, 64), 256, 0, stream>>>(
      hbuf, w2T, (void*)out, b2, x1, M_, D_, FF_);
}

// Round 2
// 252.648 us; speedup vs baseline: 1.0267x; 1.0267x over previous
//
#include <hip/hip_runtime.h>
#include <cstdint>
#include <cstddef>

// ---------------- problem constants (fixed by setup_inputs) ----------------
#define B_  4
#define T_  2048
#define D_  512
#define NH_ 8
#define HD_ 64
#define FF_ 2048
#define M_  (B_*T_)   // 8192 token rows

typedef unsigned short u16;
typedef __attribute__((ext_vector_type(8))) unsigned short u16x8;
typedef __attribute__((ext_vector_type(8))) __bf16         bf16x8;
typedef __attribute__((ext_vector_type(4))) float          f32x4;

__device__ __forceinline__ u16 f2bf(float f) {            // RNE f32 -> bf16
  unsigned u = __float_as_uint(f);
  u += 0x7FFF + ((u >> 16) & 1);
  return (u16)(u >> 16);
}

__device__ __forceinline__ f32x4 mfma_bf16(u16x8 a, u16x8 b, f32x4 c) {
  return __builtin_amdgcn_mfma_f32_16x16x32_bf16(
      __builtin_bit_cast(bf16x8, a), __builtin_bit_cast(bf16x8, b), c, 0, 0, 0);
}

// async global->LDS, 16B per lane; LDS dest = wave-uniform base + lane*16
__device__ __forceinline__ void async16(const void* g, void* l) {
  __builtin_amdgcn_global_load_lds(
      (const __attribute__((address_space(1))) unsigned int*)g,
      (__attribute__((address_space(3))) unsigned int*)l, 16, 0, 0);
}

// ---- transpose + cast: in [R][C] f32 -> out [C][R] bf16 (weights are [K][N])
__global__ __launch_bounds__(256) void trans_kernel(const float* __restrict__ in,
                                                    u16* __restrict__ out,
                                                    int R, int C) {
  __shared__ float tile[32][33];
  int c0 = blockIdx.x * 32, r0 = blockIdx.y * 32;
  int tx = threadIdx.x, ty = threadIdx.y;  // block (32,8)
#pragma unroll
  for (int i = 0; i < 4; i++)
    tile[ty + i * 8][tx] = in[(size_t)(r0 + ty + i * 8) * C + c0 + tx];
  __syncthreads();
#pragma unroll
  for (int i = 0; i < 4; i++)
    out[(size_t)(c0 + ty + i * 8) * R + r0 + tx] = f2bf(tile[tx][ty + i * 8]);
}

// ---- rmsnorm over rows of 512, fp32 in -> bf16 out. 1 wave per row.
__global__ __launch_bounds__(256) void rmsnorm_kernel(const float* __restrict__ x,
                                                      const float* __restrict__ w,
                                                      u16* __restrict__ out) {
  int row  = blockIdx.x * 4 + (threadIdx.x >> 6);
  int lane = threadIdx.x & 63;
  const float* xr = x + (size_t)row * D_ + lane * 8;
  float4 v0 = *(const float4*)xr;
  float4 v1 = *(const float4*)(xr + 4);
  float ss = v0.x*v0.x + v0.y*v0.y + v0.z*v0.z + v0.w*v0.w
           + v1.x*v1.x + v1.y*v1.y + v1.z*v1.z + v1.w*v1.w;
#pragma unroll
  for (int m = 1; m < 64; m <<= 1) ss += __shfl_xor(ss, m, 64);
  float inv = rsqrtf(ss * (1.0f / D_) + 1e-6f);
  const float* wr = w + lane * 8;
  float4 w0 = *(const float4*)wr;
  float4 w1v = *(const float4*)(wr + 4);
  u16 o[8];
  o[0] = f2bf(v0.x * inv * w0.x);  o[1] = f2bf(v0.y * inv * w0.y);
  o[2] = f2bf(v0.z * inv * w0.z);  o[3] = f2bf(v0.w * inv * w0.w);
  o[4] = f2bf(v1.x * inv * w1v.x); o[5] = f2bf(v1.y * inv * w1v.y);
  o[6] = f2bf(v1.z * inv * w1v.z); o[7] = f2bf(v1.w * inv * w1v.w);
  *(uint4*)(out + (size_t)row * D_ + lane * 8) = *(uint4*)o;
}

// ---- bf16 MFMA GEMM: C[M,N] = A[M,K] * Bt[N,K]^T (+bias)(gelu)(+res)
// BM=128, BK=64, BN template {128,64}. 256 threads = 4 waves (2x2),
// wave tile 64 x BN/2. Vectorized epilogue staged through LDS.
template <int BN, bool HAS_BIAS, bool HAS_RES, bool DO_GELU, bool STORE_BF16>
__global__ __launch_bounds__(256) void gemm_kernel(
    const u16* __restrict__ A, const u16* __restrict__ Bt, void* __restrict__ Cv,
    const float* __restrict__ bias, const float* __restrict__ res,
    int M, int N, int K) {
  constexpr int BCH = BN / 32;              // B staging chunks (4 or 2)
  constexpr int NJ  = BN / 32;              // B frags per wave (4 or 2)
  constexpr int EW  = BN + 4;               // epilogue LDS row pitch (f32)
  __shared__ __align__(16) char smem[16384 + BN * 128];
  u16* ldsA = (u16*)smem;                   // [128][64] bf16
  u16* ldsB = (u16*)(smem + 16384);         // [BN][64]  bf16
  const int tid = threadIdx.x;
  const int lane = tid & 63, w = tid >> 6;
  const int quad = lane >> 4, m16 = lane & 15;
  const int wm = w & 1, wn = w >> 1;
  const int m0 = blockIdx.y * 128, n0 = blockIdx.x * BN;

  f32x4 acc[4][NJ];
#pragma unroll
  for (int i = 0; i < 4; i++)
#pragma unroll
    for (int j = 0; j < NJ; j++) acc[i][j] = (f32x4){0.f, 0.f, 0.f, 0.f};

  const int srow = tid >> 3;          // 0..31
  const int scol = (tid & 7) * 8;     // k-offset within BK
  const u16* Ag = A  + (size_t)(m0 + srow) * K + scol;
  const u16* Bg = Bt + (size_t)(n0 + srow) * K + scol;

  for (int kt = 0; kt < K; kt += 64) {
#pragma unroll
    for (int c = 0; c < 4; c++)
      async16(Ag + (size_t)c * 32 * K + kt, smem + c * 4096 + tid * 16);
#pragma unroll
    for (int c = 0; c < BCH; c++)
      async16(Bg + (size_t)c * 32 * K + kt, smem + 16384 + c * 4096 + tid * 16);
    __syncthreads();   // drain global_load_lds before reading LDS
#pragma unroll
    for (int kk = 0; kk < 64; kk += 32) {
      const u16* pa = ldsA + (wm * 64 + m16) * 64 + kk + quad * 8;
      const u16* pb = ldsB + (wn * (BN / 2) + m16) * 64 + kk + quad * 8;
      u16x8 af[4], bfr[NJ];
#pragma unroll
      for (int i = 0; i < 4; i++) af[i] = *(const u16x8*)(pa + i * 1024);
#pragma unroll
      for (int j = 0; j < NJ; j++) bfr[j] = *(const u16x8*)(pb + j * 1024);
#pragma unroll
      for (int i = 0; i < 4; i++)
#pragma unroll
        for (int j = 0; j < NJ; j++)
          acc[i][j] = mfma_bf16(af[i], bfr[j], acc[i][j]);
    }
    __syncthreads();   // LDS reads done before next stage overwrites
  }

  // ---- epilogue: stage 32 rows x BN cols f32 in LDS per i-step, then
  // read back row-major and store full 16B/32B vectors (no partial lines).
  float* eps = (float*)smem;
#pragma unroll
  for (int i = 0; i < 4; i++) {
    __syncthreads();
#pragma unroll
    for (int j = 0; j < NJ; j++)
#pragma unroll
      for (int r = 0; r < 4; r++)
        eps[(wm * 16 + quad * 4 + r) * EW + wn * (BN / 2) + j * 16 + m16] =
            acc[i][j][r];
    __syncthreads();
    constexpr int REPS = (32 * BN) / (256 * 8);   // 2 for BN=128, 1 for BN=64
#pragma unroll
    for (int rep = 0; rep < REPS; rep++) {
      const int lr  = (BN == 128) ? (rep * 16 + (tid >> 4)) : (tid >> 3);
      const int col = (BN == 128) ? ((tid & 15) * 8) : ((tid & 7) * 8);
      const int rg  = m0 + (lr >> 4) * 64 + i * 16 + (lr & 15);
      float v[8];
      *(float4*)(v)     = *(const float4*)(eps + lr * EW + col);
      *(float4*)(v + 4) = *(const float4*)(eps + lr * EW + col + 4);
      if (HAS_BIAS) {
        float4 b0 = *(const float4*)(bias + n0 + col);
        float4 b1 = *(const float4*)(bias + n0 + col + 4);
        v[0] += b0.x; v[1] += b0.y; v[2] += b0.z; v[3] += b0.w;
        v[4] += b1.x; v[5] += b1.y; v[6] += b1.z; v[7] += b1.w;
      }
      if (DO_GELU) {
#pragma unroll
        for (int e = 0; e < 8; e++)
          v[e] = 0.5f * v[e] * (1.0f + erff(v[e] * 0.70710678118f));
      }
      const size_t idx = (size_t)rg * N + n0 + col;
      if (HAS_RES) {
        float4 r0 = *(const float4*)(res + idx);
        float4 r1 = *(const float4*)(res + idx + 4);
        v[0] += r0.x; v[1] += r0.y; v[2] += r0.z; v[3] += r0.w;
        v[4] += r1.x; v[5] += r1.y; v[6] += r1.z; v[7] += r1.w;
      }
      if (STORE_BF16) {
        u16 o[8];
#pragma unroll
        for (int e = 0; e < 8; e++) o[e] = f2bf(v[e]);
        *(uint4*)((u16*)Cv + idx) = *(uint4*)o;
      } else {
        *(float4*)((float*)Cv + idx)     = *(float4*)(v);
        *(float4*)((float*)Cv + idx + 4) = *(float4*)(v + 4);
      }
    }
  }
}

// ---- banded attention, MFMA flash-style, full-window softmax in registers.
// grid (T/64, NH, B), 256 threads = 4 waves, each wave owns 16 queries.
// qkv bf16 [B*T][1536]: q at col 0, k at 512, v at 1024 (+h*64).
__global__ __launch_bounds__(256) void attn_kernel(const u16* __restrict__ qkv,
                                                   u16* __restrict__ out) {
  __shared__ __align__(16) char smem[54272];
  u16* Ks = (u16*)smem;               // [208][64] keys (26624 B)
  u16* Vt = (u16*)(smem + 26624);     // [64][216] V transposed (27648 B)
  const int tid = threadIdx.x, lane = tid & 63, w = tid >> 6;
  const int quad = lane >> 4, m16 = lane & 15;
  const int q0 = blockIdx.x * 64, h = blockIdx.y, b = blockIdx.z;
  const int kstart = q0 - 64;         // 208-key staging window
  const u16* base = qkv + (size_t)b * T_ * 1536;

  // stage K [208][64]
  for (int c = tid; c < 1664; c += 256) {
    int row = c >> 3, cc = (c & 7) * 8;
    int j = kstart + row;
    j = j < 0 ? 0 : (j > T_ - 1 ? T_ - 1 : j);   // clamp; masked later
    *(uint4*)(Ks + row * 64 + cc) =
        *(const uint4*)(base + (size_t)j * 1536 + 512 + h * 64 + cc);
  }
  // stage V transposed -> Vt[d][key]
  for (int c = tid; c < 1664; c += 256) {
    int row = c >> 3, cc = (c & 7) * 8;
    int j = kstart + row;
    j = j < 0 ? 0 : (j > T_ - 1 ? T_ - 1 : j);
    uint4 u = *(const uint4*)(base + (size_t)j * 1536 + 1024 + h * 64 + cc);
    u16 tmp[8];
    *(uint4*)tmp = u;
#pragma unroll
    for (int i = 0; i < 8; i++) Vt[(cc + i) * 216 + row] = tmp[i];
  }
  // Q fragments straight from global (A-operand layout)
  const int qw = q0 + w * 16;
  const u16* qb = base + (size_t)(qw + m16) * 1536 + h * 64 + quad * 8;
  u16x8 a0 = *(const u16x8*)qb;
  u16x8 a1 = *(const u16x8*)(qb + 32);
  __syncthreads();

  // S = Q K^T over this wave's 160-key window (10 tiles of 16)
  float s[10][4];
#pragma unroll
  for (int t = 0; t < 10; t++) {
    int kt = (w + t) * 16;   // key index in Ks
    u16x8 kb0 = *(const u16x8*)(Ks + (kt + m16) * 64 + quad * 8);
    u16x8 kb1 = *(const u16x8*)(Ks + (kt + m16) * 64 + 32 + quad * 8);
    f32x4 acc = {0.f, 0.f, 0.f, 0.f};
    acc = mfma_bf16(a0, kb0, acc);
    acc = mfma_bf16(a1, kb1, acc);
    int jab = kstart + kt + m16;   // absolute key (col = lane&15)
#pragma unroll
    for (int r = 0; r < 4; r++) {
      int q = qw + quad * 4 + r;
      int d = q - jab;
      bool valid = (jab >= 0) && (jab < T_) && (d <= 64) && (d >= -64);
      s[t][r] = valid ? acc[r] * 0.125f : -1e30f;
    }
  }
  // softmax across 160 keys: per-lane then across the 16 lanes of each quad
  float mx[4], sm[4];
#pragma unroll
  for (int r = 0; r < 4; r++) mx[r] = -1e30f;
#pragma unroll
  for (int t = 0; t < 10; t++)
#pragma unroll
    for (int r = 0; r < 4; r++) mx[r] = fmaxf(mx[r], s[t][r]);
#pragma unroll
  for (int r = 0; r < 4; r++) {
#pragma unroll
    for (int msk = 1; msk < 16; msk <<= 1)
      mx[r] = fmaxf(mx[r], __shfl_xor(mx[r], msk, 64));
    sm[r] = 0.f;
  }
#pragma unroll
  for (int t = 0; t < 10; t++)
#pragma unroll
    for (int r = 0; r < 4; r++) {
      float e = __expf(s[t][r] - mx[r]);
      s[t][r] = e; sm[r] += e;
    }
#pragma unroll
  for (int r = 0; r < 4; r++) {
#pragma unroll
    for (int msk = 1; msk < 16; msk <<= 1) sm[r] += __shfl_xor(sm[r], msk, 64);
    sm[r] = 1.0f / sm[r];
  }
  __syncthreads();                       // all waves done reading Ks
  u16* Ps = (u16*)smem + w * 2688;       // alias Ks region: per-wave [16][168]
#pragma unroll
  for (int t = 0; t < 10; t++)
#pragma unroll
    for (int r = 0; r < 4; r++)
      Ps[(quad * 4 + r) * 168 + t * 16 + m16] = f2bf(s[t][r] * sm[r]);
  __syncthreads();

  // O = P V : A = P[16][32-chunk] (A-layout), B = Vt
  f32x4 o[4];
#pragma unroll
  for (int dt = 0; dt < 4; dt++) o[dt] = (f32x4){0.f, 0.f, 0.f, 0.f};
#pragma unroll
  for (int c5 = 0; c5 < 5; c5++) {
    u16x8 pa = *(const u16x8*)(Ps + m16 * 168 + c5 * 32 + quad * 8);
#pragma unroll
    for (int dt = 0; dt < 4; dt++) {
      u16x8 vb = *(const u16x8*)(Vt + (dt * 16 + m16) * 216 + w * 16 + c5 * 32 + quad * 8);
      o[dt] = mfma_bf16(pa, vb, o[dt]);
    }
  }
#pragma unroll
  for (int dt = 0; dt < 4; dt++)
#pragma unroll
    for (int r = 0; r < 4; r++)
      out[(size_t)(b * T_ + qw + quad * 4 + r) * D_ + h * HD_ + dt * 16 + m16] =
          f2bf(o[dt][r]);
}

// ---------------------------------------------------------------------------
extern "C" void kernel_launch(void* const* d_in, const int* in_sizes, int n_in,
                              void* d_out, int out_size, void* d_ws, size_t ws_size,
                              hipStream_t stream) {
  (void)in_sizes; (void)n_in; (void)out_size; (void)ws_size;
  const float* x     = (const float*)d_in[0];
  const float* n1w   = (const float*)d_in[1];
  const float* n2w   = (const float*)d_in[2];
  const float* w_qkv = (const float*)d_in[3];
  const float* w_out = (const float*)d_in[4];
  const float* b_out = (const float*)d_in[5];
  const float* w1    = (const float*)d_in[6];
  const float* b1    = (const float*)d_in[7];
  const float* w2    = (const float*)d_in[8];
  const float* b2    = (const float*)d_in[9];
  float* out = (float*)d_out;
  char* ws = (char*)d_ws;

  // workspace layout (62 MB; hbuf aliases dead qkv+attno, hn aliases xn)
  u16* wqkvT  = (u16*)(ws + 0);          // [1536][512]  1.5 MB
  u16* woutT  = (u16*)(ws + 1572864);    // [512][512]   0.5 MB
  u16* w1T    = (u16*)(ws + 2097152);    // [2048][512]  2 MB
  u16* w2T    = (u16*)(ws + 4194304);    // [512][2048]  2 MB
  u16* xn     = (u16*)(ws + 6291456);    // [8192][512]  8 MB (also hn)
  u16* qkv    = (u16*)(ws + 14680064);   // [8192][1536] 24 MB
  u16* attno  = (u16*)(ws + 39845888);   // [8192][512]  8 MB
  float* x1   = (float*)(ws + 48234496); // [8192][512]  16 MB
  u16* hn     = xn;
  u16* hbuf   = qkv;                     // [8192][2048] 32 MB (over qkv+attno)

  dim3 tb(32, 8);
  trans_kernel<<<dim3(48, 16), tb, 0, stream>>>(w_qkv, wqkvT, 512, 1536);
  trans_kernel<<<dim3(16, 16), tb, 0, stream>>>(w_out, woutT, 512, 512);
  trans_kernel<<<dim3(64, 16), tb, 0, stream>>>(w1,   w1T,   512, 2048);
  trans_kernel<<<dim3(16, 64), tb, 0, stream>>>(w2,   w2T,   2048, 512);

  rmsnorm_kernel<<<2048, 256, 0, stream>>>(x, n1w, xn);
  gemm_kernel<128, false, false, false, true><<<dim3(12, 64), 256, 0, stream>>>(
      xn, wqkvT, (void*)qkv, nullptr, nullptr, M_, 3 * D_, D_);
  attn_kernel<<<dim3(32, 8, 4), 256, 0, stream>>>(qkv, attno);
  gemm_kernel<64, true, true, false, false><<<dim3(8, 64), 256, 0, stream>>>(
      attno, woutT, (void*)x1, b_out, x, M_, D_, D_);
  rmsnorm_kernel<<<2048, 256, 0, stream>>>(x1, n2w, hn);
  gemm_kernel<128, true, false, true, true><<<dim3(16, 64), 256, 0, stream>>>(
      hn, w1T, (void*)hbuf, b1, nullptr, M_, FF_, D_);
  gemm_kernel<64, true, true, false, false><<<dim3(8, 64), 256, 0, stream>>>(
      hbuf, w2T, (void*)out, b2, x1, M_, D_, FF_);
}

// Round 3
// 244.764 us; speedup vs baseline: 1.0598x; 1.0322x over previous
//
#include <hip/hip_runtime.h>
#include <cstdint>
#include <cstddef>

// ---------------- problem constants (fixed by setup_inputs) ----------------
#define B_  4
#define T_  2048
#define D_  512
#define NH_ 8
#define HD_ 64
#define FF_ 2048
#define M_  (B_*T_)   // 8192 token rows

typedef unsigned short u16;
typedef __attribute__((ext_vector_type(8))) unsigned short u16x8;
typedef __attribute__((ext_vector_type(8))) __bf16         bf16x8;
typedef __attribute__((ext_vector_type(4))) float          f32x4;

__device__ __forceinline__ u16 f2bf(float f) {            // RNE f32 -> bf16
  unsigned u = __float_as_uint(f);
  u += 0x7FFF + ((u >> 16) & 1);
  return (u16)(u >> 16);
}

__device__ __forceinline__ f32x4 mfma_bf16(u16x8 a, u16x8 b, f32x4 c) {
  return __builtin_amdgcn_mfma_f32_16x16x32_bf16(
      __builtin_bit_cast(bf16x8, a), __builtin_bit_cast(bf16x8, b), c, 0, 0, 0);
}

// async global->LDS, 16B per lane; LDS dest = wave-uniform base + lane*16
__device__ __forceinline__ void async16(const void* g, void* l) {
  __builtin_amdgcn_global_load_lds(
      (const __attribute__((address_space(1))) unsigned int*)g,
      (__attribute__((address_space(3))) unsigned int*)l, 16, 0, 0);
}

// ---- transpose + cast: in [R][C] f32 -> out [C][R] bf16 (weights are [K][N])
__global__ __launch_bounds__(256) void trans_kernel(const float* __restrict__ in,
                                                    u16* __restrict__ out,
                                                    int R, int C) {
  __shared__ float tile[32][33];
  int c0 = blockIdx.x * 32, r0 = blockIdx.y * 32;
  int tx = threadIdx.x, ty = threadIdx.y;  // block (32,8)
#pragma unroll
  for (int i = 0; i < 4; i++)
    tile[ty + i * 8][tx] = in[(size_t)(r0 + ty + i * 8) * C + c0 + tx];
  __syncthreads();
#pragma unroll
  for (int i = 0; i < 4; i++)
    out[(size_t)(c0 + ty + i * 8) * R + r0 + tx] = f2bf(tile[tx][ty + i * 8]);
}

// ---- rmsnorm over rows of 512, fp32 in -> bf16 out. 1 wave per row.
__global__ __launch_bounds__(256) void rmsnorm_kernel(const float* __restrict__ x,
                                                      const float* __restrict__ w,
                                                      u16* __restrict__ out) {
  int row  = blockIdx.x * 4 + (threadIdx.x >> 6);
  int lane = threadIdx.x & 63;
  const float* xr = x + (size_t)row * D_ + lane * 8;
  float4 v0 = *(const float4*)xr;
  float4 v1 = *(const float4*)(xr + 4);
  float ss = v0.x*v0.x + v0.y*v0.y + v0.z*v0.z + v0.w*v0.w
           + v1.x*v1.x + v1.y*v1.y + v1.z*v1.z + v1.w*v1.w;
#pragma unroll
  for (int m = 1; m < 64; m <<= 1) ss += __shfl_xor(ss, m, 64);
  float inv = rsqrtf(ss * (1.0f / D_) + 1e-6f);
  const float* wr = w + lane * 8;
  float4 w0 = *(const float4*)wr;
  float4 w1v = *(const float4*)(wr + 4);
  u16 o[8];
  o[0] = f2bf(v0.x * inv * w0.x);  o[1] = f2bf(v0.y * inv * w0.y);
  o[2] = f2bf(v0.z * inv * w0.z);  o[3] = f2bf(v0.w * inv * w0.w);
  o[4] = f2bf(v1.x * inv * w1v.x); o[5] = f2bf(v1.y * inv * w1v.y);
  o[6] = f2bf(v1.z * inv * w1v.z); o[7] = f2bf(v1.w * inv * w1v.w);
  *(uint4*)(out + (size_t)row * D_ + lane * 8) = *(uint4*)o;
}

// ---- bf16 MFMA GEMM: C[M,N] = A[M,K] * Bt[N,K]^T (+bias)(gelu)(+res)
// BM=128, BK=64, BN template {128,64}. 256 threads = 4 waves (2x2),
// wave tile 64 x BN/2. XOR-swizzled LDS (16B chunk c of row r lives at
// physical slot c^(r&7)) -> conflict-free ds_read_b128 AND compatible with
// global_load_lds (we permute the global source chunk at staging time).
template <int BN, bool HAS_BIAS, bool HAS_RES, bool DO_GELU, bool STORE_BF16>
__global__ __launch_bounds__(256) void gemm_kernel(
    const u16* __restrict__ A, const u16* __restrict__ Bt, void* __restrict__ Cv,
    const float* __restrict__ bias, const float* __restrict__ res,
    int M, int N, int K) {
  constexpr int BCH = BN / 32;              // B staging chunks (4 or 2)
  constexpr int NJ  = BN / 32;              // B frags per wave (4 or 2)
  constexpr int EW  = BN + 4;               // epilogue LDS row pitch (f32)
  __shared__ __align__(16) char smem[16384 + BN * 128];
  u16* ldsA = (u16*)smem;                   // [128][64] bf16, swizzled
  u16* ldsB = (u16*)(smem + 16384);         // [BN][64]  bf16, swizzled
  const int tid = threadIdx.x;
  const int lane = tid & 63, w = tid >> 6;
  const int quad = lane >> 4, m16 = lane & 15;
  const int wm = w & 1, wn = w >> 1;
  const int m0 = blockIdx.y * 128, n0 = blockIdx.x * BN;

  f32x4 acc[4][NJ];
#pragma unroll
  for (int i = 0; i < 4; i++)
#pragma unroll
    for (int j = 0; j < NJ; j++) acc[i][j] = (f32x4){0.f, 0.f, 0.f, 0.f};

  const int srow = tid >> 3;                       // 0..31
  const int scol = (((tid & 7) ^ (srow & 7))) * 8; // swizzled source k-chunk
  const u16* Ag = A  + (size_t)(m0 + srow) * K + scol;
  const u16* Bg = Bt + (size_t)(n0 + srow) * K + scol;

  for (int kt = 0; kt < K; kt += 64) {
#pragma unroll
    for (int c = 0; c < 4; c++)
      async16(Ag + (size_t)c * 32 * K + kt, smem + c * 4096 + tid * 16);
#pragma unroll
    for (int c = 0; c < BCH; c++)
      async16(Bg + (size_t)c * 32 * K + kt, smem + 16384 + c * 4096 + tid * 16);
    __syncthreads();   // drain global_load_lds before reading LDS
#pragma unroll
    for (int kk = 0; kk < 2; kk++) {
      const int sl = ((kk * 4 + quad) ^ (m16 & 7)) * 8;  // physical slot
      const u16* pa = ldsA + (wm * 64 + m16) * 64 + sl;
      const u16* pb = ldsB + (wn * (BN / 2) + m16) * 64 + sl;
      u16x8 af[4], bfr[NJ];
#pragma unroll
      for (int i = 0; i < 4; i++) af[i] = *(const u16x8*)(pa + i * 1024);
#pragma unroll
      for (int j = 0; j < NJ; j++) bfr[j] = *(const u16x8*)(pb + j * 1024);
#pragma unroll
      for (int i = 0; i < 4; i++)
#pragma unroll
        for (int j = 0; j < NJ; j++)
          acc[i][j] = mfma_bf16(af[i], bfr[j], acc[i][j]);
    }
    __syncthreads();   // LDS reads done before next stage overwrites
  }

  // ---- epilogue: stage 32 rows x BN cols f32 in LDS per i-step, then
  // read back row-major and store full 16B/32B vectors (no partial lines).
  float* eps = (float*)smem;
#pragma unroll
  for (int i = 0; i < 4; i++) {
    __syncthreads();
#pragma unroll
    for (int j = 0; j < NJ; j++)
#pragma unroll
      for (int r = 0; r < 4; r++)
        eps[(wm * 16 + quad * 4 + r) * EW + wn * (BN / 2) + j * 16 + m16] =
            acc[i][j][r];
    __syncthreads();
    constexpr int REPS = (32 * BN) / (256 * 8);   // 2 for BN=128, 1 for BN=64
#pragma unroll
    for (int rep = 0; rep < REPS; rep++) {
      const int lr  = (BN == 128) ? (rep * 16 + (tid >> 4)) : (tid >> 3);
      const int col = (BN == 128) ? ((tid & 15) * 8) : ((tid & 7) * 8);
      const int rg  = m0 + (lr >> 4) * 64 + i * 16 + (lr & 15);
      float v[8];
      *(float4*)(v)     = *(const float4*)(eps + lr * EW + col);
      *(float4*)(v + 4) = *(const float4*)(eps + lr * EW + col + 4);
      if (HAS_BIAS) {
        float4 b0 = *(const float4*)(bias + n0 + col);
        float4 b1 = *(const float4*)(bias + n0 + col + 4);
        v[0] += b0.x; v[1] += b0.y; v[2] += b0.z; v[3] += b0.w;
        v[4] += b1.x; v[5] += b1.y; v[6] += b1.z; v[7] += b1.w;
      }
      if (DO_GELU) {
#pragma unroll
        for (int e = 0; e < 8; e++)
          v[e] = 0.5f * v[e] * (1.0f + erff(v[e] * 0.70710678118f));
      }
      const size_t idx = (size_t)rg * N + n0 + col;
      if (HAS_RES) {
        float4 r0 = *(const float4*)(res + idx);
        float4 r1 = *(const float4*)(res + idx + 4);
        v[0] += r0.x; v[1] += r0.y; v[2] += r0.z; v[3] += r0.w;
        v[4] += r1.x; v[5] += r1.y; v[6] += r1.z; v[7] += r1.w;
      }
      if (STORE_BF16) {
        u16 o[8];
#pragma unroll
        for (int e = 0; e < 8; e++) o[e] = f2bf(v[e]);
        *(uint4*)((u16*)Cv + idx) = *(uint4*)o;
      } else {
        *(float4*)((float*)Cv + idx)     = *(float4*)(v);
        *(float4*)((float*)Cv + idx + 4) = *(float4*)(v + 4);
      }
    }
  }
}

// ---- banded attention, MFMA flash-style, full-window softmax in registers.
// grid (T/64, NH, B), 256 threads = 4 waves, each wave owns 16 queries.
// qkv bf16 [B*T][1536]: q at col 0, k at 512, v at 1024 (+h*64).
// Ks pitch padded to 72 u16 (144 B) -> quad-stride 4 banks, ~2-way = free.
#define KP_ 72
__global__ __launch_bounds__(256) void attn_kernel(const u16* __restrict__ qkv,
                                                   u16* __restrict__ out) {
  __shared__ __align__(16) char smem[57600];
  u16* Ks = (u16*)smem;               // [208][72] keys (29952 B)
  u16* Vt = (u16*)(smem + 29952);     // [64][216] V transposed (27648 B)
  const int tid = threadIdx.x, lane = tid & 63, w = tid >> 6;
  const int quad = lane >> 4, m16 = lane & 15;
  const int q0 = blockIdx.x * 64, h = blockIdx.y, b = blockIdx.z;
  const int kstart = q0 - 64;         // 208-key staging window
  const u16* base = qkv + (size_t)b * T_ * 1536;

  // stage K [208][72-pitch]
  for (int c = tid; c < 1664; c += 256) {
    int row = c >> 3, cc = (c & 7) * 8;
    int j = kstart + row;
    j = j < 0 ? 0 : (j > T_ - 1 ? T_ - 1 : j);   // clamp; masked later
    *(uint4*)(Ks + row * KP_ + cc) =
        *(const uint4*)(base + (size_t)j * 1536 + 512 + h * 64 + cc);
  }
  // stage V transposed -> Vt[d][key]
  for (int c = tid; c < 1664; c += 256) {
    int row = c >> 3, cc = (c & 7) * 8;
    int j = kstart + row;
    j = j < 0 ? 0 : (j > T_ - 1 ? T_ - 1 : j);
    uint4 u = *(const uint4*)(base + (size_t)j * 1536 + 1024 + h * 64 + cc);
    u16 tmp[8];
    *(uint4*)tmp = u;
#pragma unroll
    for (int i = 0; i < 8; i++) Vt[(cc + i) * 216 + row] = tmp[i];
  }
  // Q fragments straight from global (A-operand layout)
  const int qw = q0 + w * 16;
  const u16* qb = base + (size_t)(qw + m16) * 1536 + h * 64 + quad * 8;
  u16x8 a0 = *(const u16x8*)qb;
  u16x8 a1 = *(const u16x8*)(qb + 32);
  __syncthreads();

  // S = Q K^T over this wave's 160-key window (10 tiles of 16)
  float s[10][4];
#pragma unroll
  for (int t = 0; t < 10; t++) {
    int kt = (w + t) * 16;   // key index in Ks
    u16x8 kb0 = *(const u16x8*)(Ks + (kt + m16) * KP_ + quad * 8);
    u16x8 kb1 = *(const u16x8*)(Ks + (kt + m16) * KP_ + 32 + quad * 8);
    f32x4 acc = {0.f, 0.f, 0.f, 0.f};
    acc = mfma_bf16(a0, kb0, acc);
    acc = mfma_bf16(a1, kb1, acc);
    int jab = kstart + kt + m16;   // absolute key (col = lane&15)
#pragma unroll
    for (int r = 0; r < 4; r++) {
      int q = qw + quad * 4 + r;
      int d = q - jab;
      bool valid = (jab >= 0) && (jab < T_) && (d <= 64) && (d >= -64);
      s[t][r] = valid ? acc[r] * 0.125f : -1e30f;
    }
  }
  // softmax across 160 keys: per-lane then across the 16 lanes of each quad
  float mx[4], sm[4];
#pragma unroll
  for (int r = 0; r < 4; r++) mx[r] = -1e30f;
#pragma unroll
  for (int t = 0; t < 10; t++)
#pragma unroll
    for (int r = 0; r < 4; r++) mx[r] = fmaxf(mx[r], s[t][r]);
#pragma unroll
  for (int r = 0; r < 4; r++) {
#pragma unroll
    for (int msk = 1; msk < 16; msk <<= 1)
      mx[r] = fmaxf(mx[r], __shfl_xor(mx[r], msk, 64));
    sm[r] = 0.f;
  }
#pragma unroll
  for (int t = 0; t < 10; t++)
#pragma unroll
    for (int r = 0; r < 4; r++) {
      float e = __expf(s[t][r] - mx[r]);
      s[t][r] = e; sm[r] += e;
    }
#pragma unroll
  for (int r = 0; r < 4; r++) {
#pragma unroll
    for (int msk = 1; msk < 16; msk <<= 1) sm[r] += __shfl_xor(sm[r], msk, 64);
    sm[r] = 1.0f / sm[r];
  }
  __syncthreads();                       // all waves done reading Ks
  u16* Ps = (u16*)smem + w * 2688;       // alias Ks region: per-wave [16][168]
#pragma unroll
  for (int t = 0; t < 10; t++)
#pragma unroll
    for (int r = 0; r < 4; r++)
      Ps[(quad * 4 + r) * 168 + t * 16 + m16] = f2bf(s[t][r] * sm[r]);
  __syncthreads();

  // O = P V : A = P[16][32-chunk] (A-layout), B = Vt
  f32x4 o[4];
#pragma unroll
  for (int dt = 0; dt < 4; dt++) o[dt] = (f32x4){0.f, 0.f, 0.f, 0.f};
#pragma unroll
  for (int c5 = 0; c5 < 5; c5++) {
    u16x8 pa = *(const u16x8*)(Ps + m16 * 168 + c5 * 32 + quad * 8);
#pragma unroll
    for (int dt = 0; dt < 4; dt++) {
      u16x8 vb = *(const u16x8*)(Vt + (dt * 16 + m16) * 216 + w * 16 + c5 * 32 + quad * 8);
      o[dt] = mfma_bf16(pa, vb, o[dt]);
    }
  }
#pragma unroll
  for (int dt = 0; dt < 4; dt++)
#pragma unroll
    for (int r = 0; r < 4; r++)
      out[(size_t)(b * T_ + qw + quad * 4 + r) * D_ + h * HD_ + dt * 16 + m16] =
          f2bf(o[dt][r]);
}

// ---------------------------------------------------------------------------
extern "C" void kernel_launch(void* const* d_in, const int* in_sizes, int n_in,
                              void* d_out, int out_size, void* d_ws, size_t ws_size,
                              hipStream_t stream) {
  (void)in_sizes; (void)n_in; (void)out_size; (void)ws_size;
  const float* x     = (const float*)d_in[0];
  const float* n1w   = (const float*)d_in[1];
  const float* n2w   = (const float*)d_in[2];
  const float* w_qkv = (const float*)d_in[3];
  const float* w_out = (const float*)d_in[4];
  const float* b_out = (const float*)d_in[5];
  const float* w1    = (const float*)d_in[6];
  const float* b1    = (const float*)d_in[7];
  const float* w2    = (const float*)d_in[8];
  const float* b2    = (const float*)d_in[9];
  float* out = (float*)d_out;
  char* ws = (char*)d_ws;

  // workspace layout (62 MB; hbuf aliases dead qkv+attno, hn aliases xn)
  u16* wqkvT  = (u16*)(ws + 0);          // [1536][512]  1.5 MB
  u16* woutT  = (u16*)(ws + 1572864);    // [512][512]   0.5 MB
  u16* w1T    = (u16*)(ws + 2097152);    // [2048][512]  2 MB
  u16* w2T    = (u16*)(ws + 4194304);    // [512][2048]  2 MB
  u16* xn     = (u16*)(ws + 6291456);    // [8192][512]  8 MB (also hn)
  u16* qkv    = (u16*)(ws + 14680064);   // [8192][1536] 24 MB
  u16* attno  = (u16*)(ws + 39845888);   // [8192][512]  8 MB
  float* x1   = (float*)(ws + 48234496); // [8192][512]  16 MB
  u16* hn     = xn;
  u16* hbuf   = qkv;                     // [8192][2048] 32 MB (over qkv+attno)

  dim3 tb(32, 8);
  trans_kernel<<<dim3(48, 16), tb, 0, stream>>>(w_qkv, wqkvT, 512, 1536);
  trans_kernel<<<dim3(16, 16), tb, 0, stream>>>(w_out, woutT, 512, 512);
  trans_kernel<<<dim3(64, 16), tb, 0, stream>>>(w1,   w1T,   512, 2048);
  trans_kernel<<<dim3(16, 64), tb, 0, stream>>>(w2,   w2T,   2048, 512);

  rmsnorm_kernel<<<2048, 256, 0, stream>>>(x, n1w, xn);
  gemm_kernel<128, false, false, false, true><<<dim3(12, 64), 256, 0, stream>>>(
      xn, wqkvT, (void*)qkv, nullptr, nullptr, M_, 3 * D_, D_);
  attn_kernel<<<dim3(32, 8, 4), 256, 0, stream>>>(qkv, attno);
  gemm_kernel<64, true, true, false, false><<<dim3(8, 64), 256, 0, stream>>>(
      attno, woutT, (void*)x1, b_out, x, M_, D_, D_);
  rmsnorm_kernel<<<2048, 256, 0, stream>>>(x1, n2w, hn);
  gemm_kernel<128, true, false, true, true><<<dim3(16, 64), 256, 0, stream>>>(
      hn, w1T, (void*)hbuf, b1, nullptr, M_, FF_, D_);
  gemm_kernel<64, true, true, false, false><<<dim3(8, 64), 256, 0, stream>>>(
      hbuf, w2T, (void*)out, b2, x1, M_, D_, FF_);
}